// Round 2
// baseline (472.231 us; speedup 1.0000x reference)
//
#include <hip/hip_runtime.h>
#include <math.h>

#define NCLS    16
#define B_ROWS  65536
#define MARGINc 1.0f

// ws layout (float offsets)
#define OFF_CE    0      // 1 f32 (atomic)
#define OFF_DIST  1      // 16 f32 (atomic), at [1..16]
#define OFF_CNT   32     // 16 int32 (atomic)
#define OFF_SUMS  1024   // 16*1024 f32 class sums (atomic)
#define WS_FLOATS (OFF_SUMS + NCLS * 1024)   // 17408

__global__ __launch_bounds__(256) void k_init(float* ws) {
    int i = blockIdx.x * 256 + threadIdx.x;
    if (i < WS_FLOATS) ws[i] = 0.0f;
}

#define ACC4(c, V) { acc[c].x += V.x; acc[c].y += V.y; acc[c].z += V.z; acc[c].w += V.w; }
#define SWADD(L, V) switch (L) { \
    case 0:  ACC4(0,V);  break; case 1:  ACC4(1,V);  break; \
    case 2:  ACC4(2,V);  break; case 3:  ACC4(3,V);  break; \
    case 4:  ACC4(4,V);  break; case 5:  ACC4(5,V);  break; \
    case 6:  ACC4(6,V);  break; case 7:  ACC4(7,V);  break; \
    case 8:  ACC4(8,V);  break; case 9:  ACC4(9,V);  break; \
    case 10: ACC4(10,V); break; case 11: ACC4(11,V); break; \
    case 12: ACC4(12,V); break; case 13: ACC4(13,V); break; \
    case 14: ACC4(14,V); break; case 15: ACC4(15,V); break; }

// Fused: CE partial + class counts (wave 0) and register-resident class sums
// (all waves). Block owns 64 contiguous rows; thread owns its 4-dim column slice.
__global__ __launch_bounds__(256) void k_fused(const float* __restrict__ logits,
                                               const int* __restrict__ labels,
                                               const float* __restrict__ feat,
                                               float* __restrict__ ws) {
    int tid = threadIdx.x;
    int r0 = blockIdx.x * 64;

    // --- CE + counts: wave 0 only, one row per lane ---
    if (tid < 64) {
        int row = r0 + tid;
        const float4* lg = (const float4*)(logits + (size_t)row * 16);
        float4 a = lg[0], b = lg[1], c = lg[2], d = lg[3];
        float m = fmaxf(fmaxf(fmaxf(a.x, a.y), fmaxf(a.z, a.w)),
                        fmaxf(fmaxf(b.x, b.y), fmaxf(b.z, b.w)));
        m = fmaxf(m, fmaxf(fmaxf(c.x, c.y), fmaxf(c.z, c.w)));
        m = fmaxf(m, fmaxf(fmaxf(d.x, d.y), fmaxf(d.z, d.w)));
        float s = expf(a.x - m) + expf(a.y - m) + expf(a.z - m) + expf(a.w - m)
                + expf(b.x - m) + expf(b.y - m) + expf(b.z - m) + expf(b.w - m)
                + expf(c.x - m) + expf(c.y - m) + expf(c.z - m) + expf(c.w - m)
                + expf(d.x - m) + expf(d.y - m) + expf(d.z - m) + expf(d.w - m);
        int lab = labels[row];
        float xl = logits[(size_t)row * 16 + lab];
        float ce = (m + logf(s)) - xl;
        for (int o = 32; o >= 1; o >>= 1) ce += __shfl_down(ce, o, 64);
        if (tid == 0) unsafeAtomicAdd(ws + OFF_CE, ce);
#pragma unroll
        for (int cc = 0; cc < NCLS; ++cc) {
            unsigned long long mk = __ballot(lab == cc);
            if (tid == 0 && mk) atomicAdd((int*)ws + OFF_CNT + cc, (int)__popcll(mk));
        }
    }

    // --- class sums: registers only; label is wave-uniform -> scalar switch ---
    float4 acc[NCLS];
#pragma unroll
    for (int c = 0; c < NCLS; ++c) acc[c] = make_float4(0.f, 0.f, 0.f, 0.f);
    const float4* f4 = (const float4*)feat;

    for (int r = r0; r < r0 + 64; r += 4) {
        int l0 = __builtin_amdgcn_readfirstlane(labels[r]);
        int l1 = __builtin_amdgcn_readfirstlane(labels[r + 1]);
        int l2 = __builtin_amdgcn_readfirstlane(labels[r + 2]);
        int l3 = __builtin_amdgcn_readfirstlane(labels[r + 3]);
        float4 v0 = f4[(size_t)r * 256 + tid];
        float4 v1 = f4[(size_t)(r + 1) * 256 + tid];
        float4 v2 = f4[(size_t)(r + 2) * 256 + tid];
        float4 v3 = f4[(size_t)(r + 3) * 256 + tid];
        SWADD(l0, v0);
        SWADD(l1, v1);
        SWADD(l2, v2);
        SWADD(l3, v3);
    }

    // flush: 64 f32 atomics per thread into the 64KB sums buffer
    float* sums = ws + OFF_SUMS;
#pragma unroll
    for (int c = 0; c < NCLS; ++c) {
        float* p = sums + c * 1024 + tid * 4;
        unsafeAtomicAdd(p + 0, acc[c].x);
        unsafeAtomicAdd(p + 1, acc[c].y);
        unsafeAtomicAdd(p + 2, acc[c].z);
        unsafeAtomicAdd(p + 3, acc[c].w);
    }
}

// wave-per-row distance to own-class centroid (= sums * 1/count on the fly)
__global__ __launch_bounds__(256) void k_dist(const float* __restrict__ feat,
                                              const int* __restrict__ labels,
                                              float* __restrict__ ws, int totalWaves) {
    __shared__ float wdist[4][NCLS];
    int tid = threadIdx.x, w = tid >> 6, lane = tid & 63;
    if (lane < NCLS) wdist[w][lane] = 0.f;  // own wave's row only -> no sync needed
    const float4* f4 = (const float4*)feat;
    const float4* s4 = (const float4*)(ws + OFF_SUMS);
    const int* cnts = (const int*)ws + OFF_CNT;
    int gw = blockIdx.x * 4 + w;
    for (int r = gw; r < B_ROWS; r += 2 * totalWaves) {
        int r2 = r + totalWaves;   // always < B_ROWS for our grid
        int la = labels[r], lb = labels[r2];
        int ca = cnts[la], cb = cnts[lb];
        float ia = 1.0f / (float)(ca > 0 ? ca : 1);
        float ib = 1.0f / (float)(cb > 0 ? cb : 1);
        float accA = 0.f, accB = 0.f;
#pragma unroll
        for (int k = 0; k < 4; ++k) {
            float4 v = f4[(size_t)r * 256 + k * 64 + lane];
            float4 s = s4[la * 256 + k * 64 + lane];
            float dx = v.x - s.x * ia, dy = v.y - s.y * ia;
            float dz = v.z - s.z * ia, dw = v.w - s.w * ia;
            accA += dx * dx + dy * dy + dz * dz + dw * dw;
            float4 v2 = f4[(size_t)r2 * 256 + k * 64 + lane];
            float4 s2 = s4[lb * 256 + k * 64 + lane];
            float ex = v2.x - s2.x * ib, ey = v2.y - s2.y * ib;
            float ez = v2.z - s2.z * ib, ew = v2.w - s2.w * ib;
            accB += ex * ex + ey * ey + ez * ez + ew * ew;
        }
        for (int o = 32; o >= 1; o >>= 1) {
            accA += __shfl_down(accA, o, 64);
            accB += __shfl_down(accB, o, 64);
        }
        if (lane == 0) {
            wdist[w][la] += sqrtf(accA);
            wdist[w][lb] += sqrtf(accB);
        }
    }
    __syncthreads();
    if (tid < NCLS) {
        float s = wdist[0][tid] + wdist[1][tid] + wdist[2][tid] + wdist[3][tid];
        unsafeAtomicAdd(ws + OFF_DIST + tid, s);
    }
}

// single block: inter-class pairs + final combine
__global__ __launch_bounds__(256) void k_final(float* __restrict__ ws, float* __restrict__ out) {
    __shared__ float winter[4];
    __shared__ int wcnt[4];
    int tid = threadIdx.x, w = tid >> 6, lane = tid & 63;
    const float4* s4 = (const float4*)(ws + OFF_SUMS);
    const int* cnts = (const int*)ws + OFF_CNT;
    float interAcc = 0.f; int pairAcc = 0;
    for (int p = w; p < 120; p += 4) {
        int i = 0, rem = p;
        while (rem >= 15 - i) { rem -= 15 - i; ++i; }
        int j = i + 1 + rem;
        int ci = cnts[i], cj = cnts[j];
        float ii = 1.0f / (float)(ci > 0 ? ci : 1);
        float ij = 1.0f / (float)(cj > 0 ? cj : 1);
        float acc = 0.f;
#pragma unroll
        for (int k = 0; k < 4; ++k) {
            float4 a = s4[i * 256 + k * 64 + lane];
            float4 b = s4[j * 256 + k * 64 + lane];
            float dx = a.x * ii - b.x * ij, dy = a.y * ii - b.y * ij;
            float dz = a.z * ii - b.z * ij, dw = a.w * ii - b.w * ij;
            acc += dx * dx + dy * dy + dz * dz + dw * dw;
        }
        for (int o = 32; o >= 1; o >>= 1) acc += __shfl_down(acc, o, 64);
        if (lane == 0 && ci > 0 && cj > 0) {
            float t = MARGINc - sqrtf(acc);
            if (t > 0.f) interAcc += t;
            pairAcc += 1;
        }
    }
    if (lane == 0) { winter[w] = interAcc; wcnt[w] = pairAcc; }
    __syncthreads();
    if (tid == 0) {
        float interSum = winter[0] + winter[1] + winter[2] + winter[3];
        int np = wcnt[0] + wcnt[1] + wcnt[2] + wcnt[3];
        float inter = np > 0 ? interSum / (float)np : 0.f;
        float intra = 0.f; int nv = 0;
        for (int c = 0; c < NCLS; ++c) {
            int cc = cnts[c];
            if (cc > 0) { intra += ws[OFF_DIST + c] / (float)cc; nv++; }
        }
        intra = nv > 0 ? intra / (float)nv : 0.f;
        float ce = ws[OFF_CE] / (float)B_ROWS;
        out[0] = ce + inter + intra;
    }
}

extern "C" void kernel_launch(void* const* d_in, const int* in_sizes, int n_in,
                              void* d_out, int out_size, void* d_ws, size_t ws_size,
                              hipStream_t stream) {
    const float* logits = (const float*)d_in[0];
    const int* labels   = (const int*)d_in[1];
    const float* feat   = (const float*)d_in[2];
    float* ws  = (float*)d_ws;
    float* out = (float*)d_out;

    hipLaunchKernelGGL(k_init,  dim3((WS_FLOATS + 255) / 256), dim3(256), 0, stream, ws);
    hipLaunchKernelGGL(k_fused, dim3(B_ROWS / 64),             dim3(256), 0, stream,
                       logits, labels, feat, ws);
    int nC = 2048;
    hipLaunchKernelGGL(k_dist,  dim3(nC),                      dim3(256), 0, stream,
                       feat, labels, ws, nC * 4);
    hipLaunchKernelGGL(k_final, dim3(1),                       dim3(256), 0, stream, ws, out);
}

// Round 3
// 370.690 us; speedup vs baseline: 1.2739x; 1.2739x over previous
//
#include <hip/hip_runtime.h>
#include <math.h>

#define NCLS    16
#define B_ROWS  65536
#define MARGINc 1.0f
#define NBLK    512     // k_sums blocks
#define RPB     128     // rows per block (NBLK*RPB == B_ROWS)

// ws layout (float offsets)
#define OFF_CE    0      // 1 f32 (atomic)
#define OFF_DIST  1      // 16 f32 (atomic), at [1..16]
#define OFF_CNT   32     // 16 int32 (atomic)
#define OFF_CENT  1024   // 16*1024 f32 centroids
#define OFF_PART  32768  // NBLK * 16384 f32 partial sums
#define WS_ZERO   64     // floats zeroed by k_init

__global__ __launch_bounds__(64) void k_init(float* ws) {
    int t = threadIdx.x;
    if (t < WS_ZERO) ws[t] = 0.0f;  // CE, DIST[16], CNT[16]
}

// named-register accumulate: arms pinned distinct via empty asm so the
// compiler cannot re-merge into an indexed (scratch) array  [R2 post-mortem]
#define ARM(ACC, V) { ACC.x += V.x; ACC.y += V.y; ACC.z += V.z; ACC.w += V.w; \
    asm volatile("" : "+v"(ACC.x), "+v"(ACC.y), "+v"(ACC.z), "+v"(ACC.w)); }
#define CHAIN(L, V) { const int _l = (L); \
    if      (_l == 0)  ARM(a0,  V) \
    else if (_l == 1)  ARM(a1,  V) \
    else if (_l == 2)  ARM(a2,  V) \
    else if (_l == 3)  ARM(a3,  V) \
    else if (_l == 4)  ARM(a4,  V) \
    else if (_l == 5)  ARM(a5,  V) \
    else if (_l == 6)  ARM(a6,  V) \
    else if (_l == 7)  ARM(a7,  V) \
    else if (_l == 8)  ARM(a8,  V) \
    else if (_l == 9)  ARM(a9,  V) \
    else if (_l == 10) ARM(a10, V) \
    else if (_l == 11) ARM(a11, V) \
    else if (_l == 12) ARM(a12, V) \
    else if (_l == 13) ARM(a13, V) \
    else               ARM(a15, V) \
    }
#define CHAIN14(L, V) { if ((L) == 14) ARM(a14, V) }

// Fused: class sums in named registers (all waves) + CE/counts (waves 0-1).
// Block owns RPB contiguous rows; thread owns dims [4*tid, 4*tid+4).
__global__ __launch_bounds__(256) void k_sums_ce(const float* __restrict__ logits,
                                                 const int* __restrict__ labels,
                                                 const float* __restrict__ feat,
                                                 float* __restrict__ ws) {
    int tid = threadIdx.x;
    int r0 = blockIdx.x * RPB;

    // --- CE + counts: first 2 waves, one row per lane (RPB == 128) ---
    if (tid < 128) {
        int row = r0 + tid;
        const float4* lg = (const float4*)(logits + (size_t)row * 16);
        float4 a = lg[0], b = lg[1], c = lg[2], d = lg[3];
        float m = fmaxf(fmaxf(fmaxf(a.x, a.y), fmaxf(a.z, a.w)),
                        fmaxf(fmaxf(b.x, b.y), fmaxf(b.z, b.w)));
        m = fmaxf(m, fmaxf(fmaxf(c.x, c.y), fmaxf(c.z, c.w)));
        m = fmaxf(m, fmaxf(fmaxf(d.x, d.y), fmaxf(d.z, d.w)));
        float s = expf(a.x - m) + expf(a.y - m) + expf(a.z - m) + expf(a.w - m)
                + expf(b.x - m) + expf(b.y - m) + expf(b.z - m) + expf(b.w - m)
                + expf(c.x - m) + expf(c.y - m) + expf(c.z - m) + expf(c.w - m)
                + expf(d.x - m) + expf(d.y - m) + expf(d.z - m) + expf(d.w - m);
        int lab = labels[row];
        float xl = logits[(size_t)row * 16 + lab];
        float ce = (m + logf(s)) - xl;
        for (int o = 32; o >= 1; o >>= 1) ce += __shfl_down(ce, o, 64);
        if ((tid & 63) == 0) unsafeAtomicAdd(ws + OFF_CE, ce);
#pragma unroll
        for (int cc = 0; cc < NCLS; ++cc) {
            unsigned long long mk = __ballot(lab == cc);
            if ((tid & 63) == 0 && mk) atomicAdd((int*)ws + OFF_CNT + cc, (int)__popcll(mk));
        }
    }

    // --- class sums in 16 named float4 registers ---
    float4 a0, a1, a2, a3, a4, a5, a6, a7, a8, a9, a10, a11, a12, a13, a14, a15;
    a0 = a1 = a2 = a3 = a4 = a5 = a6 = a7 = make_float4(0.f, 0.f, 0.f, 0.f);
    a8 = a9 = a10 = a11 = a12 = a13 = a14 = a15 = make_float4(0.f, 0.f, 0.f, 0.f);

    const float4* f4 = (const float4*)feat;
    for (int r = r0; r < r0 + RPB; r += 8) {
        int4 lA = *(const int4*)(labels + r);
        int4 lB = *(const int4*)(labels + r + 4);
        float4 v0 = f4[(size_t)(r + 0) * 256 + tid];
        float4 v1 = f4[(size_t)(r + 1) * 256 + tid];
        float4 v2 = f4[(size_t)(r + 2) * 256 + tid];
        float4 v3 = f4[(size_t)(r + 3) * 256 + tid];
        float4 v4 = f4[(size_t)(r + 4) * 256 + tid];
        float4 v5 = f4[(size_t)(r + 5) * 256 + tid];
        float4 v6 = f4[(size_t)(r + 6) * 256 + tid];
        float4 v7 = f4[(size_t)(r + 7) * 256 + tid];
        int s0 = __builtin_amdgcn_readfirstlane(lA.x);
        int s1 = __builtin_amdgcn_readfirstlane(lA.y);
        int s2 = __builtin_amdgcn_readfirstlane(lA.z);
        int s3 = __builtin_amdgcn_readfirstlane(lA.w);
        int s4 = __builtin_amdgcn_readfirstlane(lB.x);
        int s5 = __builtin_amdgcn_readfirstlane(lB.y);
        int s6 = __builtin_amdgcn_readfirstlane(lB.z);
        int s7 = __builtin_amdgcn_readfirstlane(lB.w);
        CHAIN(s0, v0) CHAIN14(s0, v0)
        CHAIN(s1, v1) CHAIN14(s1, v1)
        CHAIN(s2, v2) CHAIN14(s2, v2)
        CHAIN(s3, v3) CHAIN14(s3, v3)
        CHAIN(s4, v4) CHAIN14(s4, v4)
        CHAIN(s5, v5) CHAIN14(s5, v5)
        CHAIN(s6, v6) CHAIN14(s6, v6)
        CHAIN(s7, v7) CHAIN14(s7, v7)
    }

    // flush: per-block partials, coalesced float4 stores (no atomics)
    float4* p = (float4*)(ws + OFF_PART + (size_t)blockIdx.x * 16384);
    p[0 * 256 + tid]  = a0;  p[1 * 256 + tid]  = a1;
    p[2 * 256 + tid]  = a2;  p[3 * 256 + tid]  = a3;
    p[4 * 256 + tid]  = a4;  p[5 * 256 + tid]  = a5;
    p[6 * 256 + tid]  = a6;  p[7 * 256 + tid]  = a7;
    p[8 * 256 + tid]  = a8;  p[9 * 256 + tid]  = a9;
    p[10 * 256 + tid] = a10; p[11 * 256 + tid] = a11;
    p[12 * 256 + tid] = a12; p[13 * 256 + tid] = a13;
    p[14 * 256 + tid] = a14; p[15 * 256 + tid] = a15;
}

// reduce partials -> true centroids (divided by safe count)
__global__ __launch_bounds__(128) void k_cent(float* __restrict__ ws) {
    int j = blockIdx.x * 128 + threadIdx.x;   // 0..16383, grid 128 blocks
    const float* part = ws + OFF_PART;
    float s = 0.f;
    for (int a = 0; a < NBLK; ++a) s += part[(size_t)a * 16384 + j];
    int c = j >> 10;
    int cnt = ((const int*)ws)[OFF_CNT + c];
    float safe = cnt > 0 ? (float)cnt : 1.0f;
    ws[OFF_CENT + j] = s / safe;
}

// wave-per-row distance to own-class centroid; centroids stay in L2 (64KB)
__global__ __launch_bounds__(256) void k_dist(const float* __restrict__ feat,
                                              const int* __restrict__ labels,
                                              float* __restrict__ ws, int totalWaves) {
    __shared__ float wdist[4][NCLS];
    int tid = threadIdx.x, w = tid >> 6, lane = tid & 63;
    if (lane < NCLS) wdist[w][lane] = 0.f;  // own wave's row only
    const float4* f4 = (const float4*)feat;
    const float4* c4 = (const float4*)(ws + OFF_CENT);
    int gw = blockIdx.x * 4 + w;
    for (int r = gw; r < B_ROWS; r += 2 * totalWaves) {
        int r2 = r + totalWaves;   // < B_ROWS for our grid
        int la = labels[r], lb = labels[r2];
        float accA = 0.f, accB = 0.f;
#pragma unroll
        for (int k = 0; k < 4; ++k) {
            float4 v = f4[(size_t)r * 256 + k * 64 + lane];
            float4 c = c4[la * 256 + k * 64 + lane];
            float dx = v.x - c.x, dy = v.y - c.y, dz = v.z - c.z, dw = v.w - c.w;
            accA += dx * dx + dy * dy + dz * dz + dw * dw;
            float4 v2 = f4[(size_t)r2 * 256 + k * 64 + lane];
            float4 c2 = c4[lb * 256 + k * 64 + lane];
            float ex = v2.x - c2.x, ey = v2.y - c2.y, ez = v2.z - c2.z, ew = v2.w - c2.w;
            accB += ex * ex + ey * ey + ez * ez + ew * ew;
        }
        for (int o = 32; o >= 1; o >>= 1) {
            accA += __shfl_down(accA, o, 64);
            accB += __shfl_down(accB, o, 64);
        }
        if (lane == 0) {
            wdist[w][la] += sqrtf(accA);
            wdist[w][lb] += sqrtf(accB);
        }
    }
    __syncthreads();
    if (tid < NCLS) {
        float s = wdist[0][tid] + wdist[1][tid] + wdist[2][tid] + wdist[3][tid];
        unsafeAtomicAdd(ws + OFF_DIST + tid, s);
    }
}

// single block: inter-class pairs + final combine
__global__ __launch_bounds__(256) void k_final(float* __restrict__ ws, float* __restrict__ out) {
    __shared__ float winter[4];
    __shared__ int wcnt[4];
    int tid = threadIdx.x, w = tid >> 6, lane = tid & 63;
    const float4* c4 = (const float4*)(ws + OFF_CENT);
    const int* cnts = (const int*)ws + OFF_CNT;
    float interAcc = 0.f; int pairAcc = 0;
    for (int p = w; p < 120; p += 4) {
        int i = 0, rem = p;
        while (rem >= 15 - i) { rem -= 15 - i; ++i; }
        int j = i + 1 + rem;
        int ci = cnts[i], cj = cnts[j];
        float acc = 0.f;
#pragma unroll
        for (int k = 0; k < 4; ++k) {
            float4 a = c4[i * 256 + k * 64 + lane];
            float4 b = c4[j * 256 + k * 64 + lane];
            float dx = a.x - b.x, dy = a.y - b.y, dz = a.z - b.z, dw = a.w - b.w;
            acc += dx * dx + dy * dy + dz * dz + dw * dw;
        }
        for (int o = 32; o >= 1; o >>= 1) acc += __shfl_down(acc, o, 64);
        if (lane == 0 && ci > 0 && cj > 0) {
            float t = MARGINc - sqrtf(acc);
            if (t > 0.f) interAcc += t;
            pairAcc += 1;
        }
    }
    if (lane == 0) { winter[w] = interAcc; wcnt[w] = pairAcc; }
    __syncthreads();
    if (tid == 0) {
        float interSum = winter[0] + winter[1] + winter[2] + winter[3];
        int np = wcnt[0] + wcnt[1] + wcnt[2] + wcnt[3];
        float inter = np > 0 ? interSum / (float)np : 0.f;
        float intra = 0.f; int nv = 0;
        for (int c = 0; c < NCLS; ++c) {
            int cc = cnts[c];
            if (cc > 0) { intra += ws[OFF_DIST + c] / (float)cc; nv++; }
        }
        intra = nv > 0 ? intra / (float)nv : 0.f;
        float ce = ws[OFF_CE] / (float)B_ROWS;
        out[0] = ce + inter + intra;
    }
}

extern "C" void kernel_launch(void* const* d_in, const int* in_sizes, int n_in,
                              void* d_out, int out_size, void* d_ws, size_t ws_size,
                              hipStream_t stream) {
    const float* logits = (const float*)d_in[0];
    const int* labels   = (const int*)d_in[1];
    const float* feat   = (const float*)d_in[2];
    float* ws  = (float*)d_ws;
    float* out = (float*)d_out;

    hipLaunchKernelGGL(k_init,    dim3(1),    dim3(64),  0, stream, ws);
    hipLaunchKernelGGL(k_sums_ce, dim3(NBLK), dim3(256), 0, stream, logits, labels, feat, ws);
    hipLaunchKernelGGL(k_cent,    dim3(128),  dim3(128), 0, stream, ws);
    int nC = 2048;
    hipLaunchKernelGGL(k_dist,    dim3(nC),   dim3(256), 0, stream, feat, labels, ws, nC * 4);
    hipLaunchKernelGGL(k_final,   dim3(1),    dim3(256), 0, stream, ws, out);
}